// Round 15
// baseline (361.489 us; speedup 1.0000x reference)
//
#include <hip/hip_runtime.h>
#include <hip/hip_bf16.h>

#define NSPEC 4
#define NFEAT 144
#define RCUT 5.0f
#define RPB 64                 // centers per bucket
#define MAXB 1568              // max buckets (NC <= 100352)
#define CAP 1536               // pairs capacity per bucket
#define CHUNK 8192             // pairs per partition block
#define PBDIM 1024             // mega-kernel block threads (16 waves)
#define IPT (CHUNK / PBDIM)    // items per thread = 8
#define ASTRIDE 148            // accum stage stride (floats)

// LDS layout (ints). Partition: sSort[8192] | sHist[MAXB] | sOffs[MAXB] | wtot[16]
// Accum:  sStage[64*148] | sSort[1536] | sHist[256] | sOff[256] | wtot[16] | dest[64]
#define LDSN 11680
#define P_SORT 0
#define P_HIST 8192
#define P_OFFS (8192 + MAXB)
#define P_WTOT (8192 + 2 * MAXB)
#define A_STAGE 0
#define A_SORT 9472
#define A_HIST 11008
#define A_OFF 11264
#define A_WTOT 11520
#define A_DEST 11536

__device__ __forceinline__ int aload(const int* p) {
    return __hip_atomic_load(p, __ATOMIC_RELAXED, __HIP_MEMORY_SCOPE_AGENT);
}
__device__ __forceinline__ unsigned aloadu(const unsigned* p) {
    return __hip_atomic_load(p, __ATOMIC_RELAXED, __HIP_MEMORY_SCOPE_AGENT);
}
__device__ __forceinline__ int aload_acq(const int* p) {
    return __hip_atomic_load(p, __ATOMIC_ACQUIRE, __HIP_MEMORY_SCOPE_AGENT);
}

// ---------- utility ----------

__global__ void zero_f32(float* __restrict__ out, int n) {
    int n4 = n >> 2;
    float4* o4 = (float4*)out;
    for (int i = blockIdx.x * blockDim.x + threadIdx.x; i < n4; i += gridDim.x * blockDim.x)
        o4[i] = make_float4(0.f, 0.f, 0.f, 0.f);
    int tail = n & 3;
    if (blockIdx.x == 0 && threadIdx.x < tail) out[n4 * 4 + threadIdx.x] = 0.f;
}

// ---------- prep: per-chunk species counts + control zeroing ----------

__global__ void prep_kernel(const int* __restrict__ cs, int n, int* __restrict__ chunkCounts,
                            int* __restrict__ zeroPtr, int zeroN) {
    __shared__ int cnt[NSPEC];
    if (threadIdx.x < NSPEC) cnt[threadIdx.x] = 0;
    __syncthreads();
    int i = blockIdx.x * blockDim.x + threadIdx.x;
    if (i < n) atomicAdd(&cnt[cs[i]], 1);
    if (zeroPtr) {
        for (int j = i; j < zeroN; j += gridDim.x * blockDim.x) zeroPtr[j] = 0;
    }
    __syncthreads();
    if (threadIdx.x < NSPEC) chunkCounts[blockIdx.x * NSPEC + threadIdx.x] = cnt[threadIdx.x];
}

// ---------- inline accum job (called from mega kernel epilogue) ----------

__device__ void accum_job(int j, int* ldsraw, const int* gCursor, const unsigned* gBucket,
                          const int* dest, float* out, int NC) {
    float* sStage = (float*)(ldsraw + A_STAGE);
    unsigned* sSort = (unsigned*)(ldsraw + A_SORT);
    int* sHist = ldsraw + A_HIST;
    int* sOff = ldsraw + A_OFF;
    int* sWaveTot = ldsraw + A_WTOT;
    int* destLds = ldsraw + A_DEST;

    int tid = threadIdx.x;
    int cBase = j * RPB;
    int n = min(aload(&gCursor[j]), CAP);
    const unsigned* src = gBucket + (size_t)j * CAP;

    if (tid < 256) sHist[tid] = 0;
    if (tid < RPB && cBase + tid < NC) destLds[tid] = aload(&dest[cBase + tid]);
    __syncthreads();

    for (int i = tid; i < n; i += PBDIM) atomicAdd(&sHist[aloadu(&src[i]) & 255u], 1);
    __syncthreads();

    int lane = tid & 63, wv = tid >> 6;
    int v = 0, incl = 0;
    if (tid < 256) {
        v = sHist[tid];
        incl = v;
        #pragma unroll
        for (int off = 1; off < 64; off <<= 1) {
            int t = __shfl_up(incl, off);
            if (lane >= off) incl += t;
        }
        if (lane == 63) sWaveTot[wv] = incl;
    }
    __syncthreads();
    if (tid < 256) {
        int wbase = 0;
        for (int w = 0; w < wv; ++w) wbase += sWaveTot[w];
        sOff[tid] = wbase + incl - v;
    }
    __syncthreads();

    for (int i = tid; i < n; i += PBDIM) {
        unsigned u = aloadu(&src[i]);
        int pos = atomicAdd(&sOff[u & 255u], 1);
        sSort[pos] = u;
    }
    __syncthreads();

    // 4 threads per bin: parity (tid&1) splits pairs; half ((tid>>1)&1) splits outputs
    int k = tid >> 2;
    int half = (tid >> 1) & 1;
    int parity = tid & 1;
    int end = sOff[k], start = end - sHist[k];
    float acc[18];
    #pragma unroll
    for (int t = 0; t < 18; ++t) acc[t] = 0.f;

    for (int p = start + parity; p < end; p += 2) {
        unsigned u = sSort[p];
        float r = __uint_as_float(u & 0xFFFFFF00u);
        float r2 = r * r;
        float fc = 0.5f * (__cosf(0.6283185307179586f * r) + 1.0f);
        float q = __expf(-r2 * 0.04f);
        float q2 = q * q;
        float bq[12];
        bq[0] = q; bq[1] = q2;
        #pragma unroll
        for (int t = 2; t < 12; ++t) bq[t] = bq[t - 2] * q2;
        float a0 = fc, a1 = fc * r, a2 = a1 * r, a3 = a2 * r;
        if (half == 0) {
            #pragma unroll
            for (int t = 0; t < 12; ++t) acc[t] = fmaf(a0, bq[t], acc[t]);
            #pragma unroll
            for (int t = 0; t < 6; ++t) acc[12 + t] = fmaf(a1, bq[t], acc[12 + t]);
        } else {
            #pragma unroll
            for (int t = 0; t < 4; ++t) acc[t] = fmaf(a1, bq[6 + t], acc[t]);
            #pragma unroll
            for (int t = 0; t < 8; ++t) acc[4 + t] = fmaf(a2, bq[t], acc[4 + t]);
            #pragma unroll
            for (int t = 0; t < 6; ++t) acc[12 + t] = fmaf(a3, bq[t], acc[12 + t]);
        }
    }
    #pragma unroll
    for (int t = 0; t < 18; ++t) acc[t] += __shfl_xor(acc[t], 1);

    if (parity == 0) {
        float* rowp = sStage + (k >> 2) * ASTRIDE + (k & 3);
        if (half == 0) {
            #pragma unroll
            for (int t = 0; t < 12; ++t) rowp[t * 4] = acc[t];
            #pragma unroll
            for (int t = 0; t < 6; ++t) rowp[48 + t * 4] = acc[12 + t];
        } else {
            #pragma unroll
            for (int t = 0; t < 4; ++t) rowp[48 + (6 + t) * 4] = acc[t];
            #pragma unroll
            for (int t = 0; t < 8; ++t) rowp[88 + t * 4] = acc[4 + t];
            #pragma unroll
            for (int t = 0; t < 6; ++t) rowp[120 + t * 4] = acc[12 + t];
        }
    }
    __syncthreads();

    int nRows = min(RPB, NC - cBase);
    int lim = nRows * 36;
    for (int i = tid; i < lim; i += PBDIM) {
        int row = i / 36;
        int c4 = i - row * 36;
        float4 val = *(const float4*)(sStage + row * ASTRIDE + c4 * 4);
        *(float4*)(out + (size_t)destLds[row] * NFEAT + c4 * 4) = val;
    }
    __syncthreads();
}

// ---------- mega kernel: partition + dest + inline work-stealing accum ----------
// payload u: bits[31:8] = r (low 8 mantissa bits replaced), bits[7:2] = center&63,
// bits[1:0] = species.

__global__ void __launch_bounds__(PBDIM, 8) mega_kernel(
        const float* __restrict__ dirs, const int* __restrict__ pci,
        const int* __restrict__ nsi, const int* __restrict__ cs,
        const int* __restrict__ chunkCounts, int* __restrict__ dest,
        int* __restrict__ gCursor, int* __restrict__ doneCnt,
        int* __restrict__ ticket, int* __restrict__ destDone,
        unsigned* __restrict__ gBucket, float* __restrict__ out,
        int P, int NC, int nbk, int nChunks, int nPart) {
    __shared__ int ldsraw[LDSN];
    __shared__ int sT;

    int tid = threadIdx.x;
    int lane = tid & 63, wv = tid >> 6;

    if ((int)blockIdx.x < nPart) {
        // ---------------- partition job ----------------
        unsigned* sSort = (unsigned*)(ldsraw + P_SORT);
        int* sHist = ldsraw + P_HIST;
        int* sOffs = ldsraw + P_OFFS;
        int* sWaveTot = ldsraw + P_WTOT;

        int base = blockIdx.x * CHUNK;

        for (int i = tid; i < nbk; i += PBDIM) sHist[i] = 0;
        __syncthreads();

        unsigned uu[IPT];
        int bb[IPT];
        #pragma unroll
        for (int jj = 0; jj < IPT; ++jj) {
            int i = base + jj * PBDIM + tid;
            int bkt = -1; unsigned u = 0;
            if (i < P) {
                float x = dirs[3 * i + 0], y = dirs[3 * i + 1], z = dirs[3 * i + 2];
                float r2 = x * x + y * y + z * z;
                if (r2 < RCUT * RCUT) {
                    float r = sqrtf(r2);
                    int c = pci[i];
                    bkt = c >> 6;
                    u = (__float_as_uint(r) & 0xFFFFFF00u) | ((unsigned)(c & 63) << 2) |
                        (unsigned)nsi[i];
                    atomicAdd(&sHist[bkt], 1);
                }
            }
            uu[jj] = u; bb[jj] = bkt;
        }
        __syncthreads();

        // block exclusive scan of sHist[0..nbk) into sOffs
        int seg = (nbk + PBDIM - 1) / PBDIM;
        int s0 = tid * seg;
        int run = 0;
        for (int kk = 0; kk < seg; ++kk) {
            int idx = s0 + kk;
            if (idx < nbk) { sOffs[idx] = run; run += sHist[idx]; }
        }
        int incl = run;
        #pragma unroll
        for (int off = 1; off < 64; off <<= 1) {
            int t = __shfl_up(incl, off);
            if (lane >= off) incl += t;
        }
        if (lane == 63) sWaveTot[wv] = incl;
        __syncthreads();
        int wbase = 0;
        for (int w = 0; w < wv; ++w) wbase += sWaveTot[w];
        int exc = wbase + incl - run;
        for (int kk = 0; kk < seg; ++kk) {
            int idx = s0 + kk;
            if (idx < nbk) sOffs[idx] += exc;
        }
        __syncthreads();

        // scatter into LDS sorted order
        #pragma unroll
        for (int jj = 0; jj < IPT; ++jj) {
            if (bb[jj] >= 0) {
                int pos = atomicAdd(&sOffs[bb[jj]], 1);
                sSort[pos] = uu[jj];
            }
        }
        __syncthreads();

        // flush buckets (single-writer per bucket within block)
        for (int b = tid; b < nbk; b += PBDIM) {
            int c = sHist[b];
            if (c) {
                int start = sOffs[b] - c;
                int g = atomicAdd(&gCursor[b], c);
                int lim = min(c, CAP - g);
                unsigned* dst = gBucket + (size_t)b * CAP + g;
                for (int kk = 0; kk < lim; ++kk) dst[kk] = sSort[start + kk];
            }
        }
        // release: my stores, then my buckets' done counts
        __threadfence();
        for (int b = tid; b < nbk; b += PBDIM) atomicAdd(&doneCnt[b], 1);

        // ---------------- work-stealing accum epilogue ----------------
        __syncthreads();  // LDS reuse safety
        if (tid == 0) {
            while (aload_acq(destDone) < nChunks) __builtin_amdgcn_s_sleep(32);
        }
        __syncthreads();

        while (true) {
            if (tid == 0) {
                int t = atomicAdd(ticket, 1);
                sT = t;
                if (t < nbk) {
                    while (aload_acq(&doneCnt[t]) < nPart) __builtin_amdgcn_s_sleep(16);
                }
            }
            __syncthreads();
            int j = sT;
            if (j >= nbk) break;
            accum_job(j, ldsraw, gCursor, gBucket, dest, out, NC);
        }
    } else {
        // ---------------- dest job: chunk cj (atomic-free wave reduce) ----------------
        int cj = blockIdx.x - nPart;
        if (cj >= nChunks) return;
        int* cOffs = ldsraw;          // 4
        int* wPart = ldsraw + 8;      // 16*2
        int* spAcc = ldsraw + 48;     // 8
        int* wCnt  = ldsraw + 64;     // 16*4

        int sp = wv & 3;
        int pref = 0, tot = 0;
        for (int c = (wv >> 2) * 64 + lane; c < nChunks; c += 256) {
            int v = chunkCounts[c * NSPEC + sp];
            tot += v;
            if (c < cj) pref += v;
        }
        #pragma unroll
        for (int off = 32; off; off >>= 1) {
            pref += __shfl_down(pref, off);
            tot  += __shfl_down(tot, off);
        }
        if (lane == 0) { wPart[wv * 2] = pref; wPart[wv * 2 + 1] = tot; }
        __syncthreads();

        if (tid < 4) {
            int p = 0, t = 0;
            for (int w = tid; w < 16; w += 4) { p += wPart[w * 2]; t += wPart[w * 2 + 1]; }
            spAcc[tid] = p; spAcc[4 + tid] = t;
        }
        __syncthreads();
        if (tid == 0) {
            int b = 0;
            #pragma unroll
            for (int s = 0; s < NSPEC; ++s) { cOffs[s] = b + spAcc[s]; b += spAcc[4 + s]; }
        }
        __syncthreads();

        int i = cj * 256 + tid;
        int s = (tid < 256 && i < NC) ? cs[i] : -1;
        int lanePrefix = 0;
        #pragma unroll
        for (int spp = 0; spp < NSPEC; ++spp) {
            unsigned long long b = __ballot(s == spp);
            if (lane == 0) wCnt[wv * 4 + spp] = __popcll(b);
            if (spp == s) lanePrefix = __popcll(b & ((1ull << lane) - 1ull));
        }
        __syncthreads();
        if (s >= 0) {
            int wp = 0;
            for (int w = 0; w < wv; ++w) wp += wCnt[w * 4 + s];
            dest[i] = cOffs[s] + wp + lanePrefix;
        }
        // release dest[] then signal
        __threadfence();
        __syncthreads();
        if (tid == 0) atomicAdd(destDone, 1);
    }
}

// ---------- fallback: direct atomic scatter ----------

__global__ void pair_kernel(const float* __restrict__ dirs,
                            const int* __restrict__ pci,
                            const int* __restrict__ nsi,
                            const int* __restrict__ dest,
                            float* __restrict__ out, int P) {
    int i = blockIdx.x * blockDim.x + threadIdx.x;
    if (i >= P) return;
    float x = dirs[3 * i + 0], y = dirs[3 * i + 1], z = dirs[3 * i + 2];
    float r2 = x * x + y * y + z * z;
    float r = sqrtf(r2);
    if (r >= RCUT) return;
    float fc = 0.5f * (cosf(3.14159265358979323846f * r * (1.0f / RCUT)) + 1.0f);
    float q = expf(-r2 * (1.0f / (RCUT * RCUT)));
    int rowb = dest[pci[i]] * NFEAT;
    int s = nsi[i];
    float* o = out + rowb + s;
    float rl = fc;
    const int nmax[4] = {12, 10, 8, 6};
    const int offl[4] = {0, 48, 88, 120};
    #pragma unroll
    for (int l = 0; l < 4; ++l) {
        float e = q;
        for (int n = 0; n < nmax[l]; ++n) { atomicAdd(o + offl[l] + n * NSPEC, rl * e); e *= q; }
        rl *= r;
    }
}

extern "C" void kernel_launch(void* const* d_in, const int* in_sizes, int n_in,
                              void* d_out, int out_size, void* d_ws, size_t ws_size,
                              hipStream_t stream) {
    const float* dirs = (const float*)d_in[0];
    const int* pci = (const int*)d_in[1];
    const int* nsi = (const int*)d_in[2];
    const int* cs = (const int*)d_in[3];
    int P = in_sizes[1];
    int NC = in_sizes[3];
    float* out = (float*)d_out;

    int nChunks = (NC + 255) / 256;
    int nbk = (NC + RPB - 1) / RPB;
    int nPart = (P + CHUNK - 1) / CHUNK;

    // ws layout (ints): counts | dest | gCursor | doneCnt | ticket | destDone | gBucket
    int* chunkCounts = (int*)d_ws;                       // nChunks*4
    int* dest        = chunkCounts + nChunks * NSPEC;    // NC
    int* gCursor     = dest + NC;                        // nbk
    int* doneCnt     = gCursor + nbk;                    // nbk
    int* ticket      = doneCnt + nbk;                    // 1
    int* destDone    = ticket + 1;                       // 1
    unsigned* gBucket = (unsigned*)(destDone + 1);       // nbk*CAP

    size_t need = ((size_t)(nChunks * NSPEC) + (size_t)NC + 2 * (size_t)nbk + 2 +
                   (size_t)nbk * CAP) * sizeof(int);
    bool fastPath = (ws_size >= need) && (nbk <= MAXB);

    if (fastPath) {
        // zero region: gCursor .. destDone (2*nbk + 2 ints, contiguous)
        prep_kernel<<<nChunks, 256, 0, stream>>>(cs, NC, chunkCounts, gCursor, 2 * nbk + 2);
        mega_kernel<<<nPart + nChunks, PBDIM, 0, stream>>>(
            dirs, pci, nsi, cs, chunkCounts, dest, gCursor, doneCnt, ticket, destDone,
            gBucket, out, P, NC, nbk, nChunks, nPart);
    } else {
        prep_kernel<<<nChunks, 256, 0, stream>>>(cs, NC, chunkCounts, (int*)nullptr, 0);
        mega_kernel<<<nChunks, PBDIM, 0, stream>>>(
            dirs, pci, nsi, cs, chunkCounts, dest, gCursor, doneCnt, ticket, destDone,
            (unsigned*)d_ws, out, 0 /*P=0 -> no partition blocks*/, NC, nbk, nChunks, 0);
        zero_f32<<<2048, 256, 0, stream>>>(out, out_size);
        pair_kernel<<<(P + 255) / 256, 256, 0, stream>>>(dirs, pci, nsi, dest, out, P);
    }
}

// Round 16
// 47.494 us; speedup vs baseline: 7.6112x; 7.6112x over previous
//
#include <hip/hip_runtime.h>
#include <hip/hip_bf16.h>

#define NSPEC 4
#define NFEAT 144
#define RCUT 5.0f
#define CPB 256                // centers per coarse bucket
#define MAXBC 400              // max coarse buckets (NC <= 102400)
#define CAP 5120               // pairs capacity per bucket (avg ~4600, +7.6 sigma)
#define CHUNK 8192             // pairs per partition block
#define PBDIM 1024             // block threads (16 waves)
#define IPT (CHUNK / PBDIM)    // items per thread = 8
#define ASTRIDE 148            // accum stage stride (floats)
#define PLDSN (CHUNK + 2 * MAXBC + 16 + 128)

// ---------- utility ----------

__global__ void zero_f32(float* __restrict__ out, int n) {
    int n4 = n >> 2;
    float4* o4 = (float4*)out;
    for (int i = blockIdx.x * blockDim.x + threadIdx.x; i < n4; i += gridDim.x * blockDim.x)
        o4[i] = make_float4(0.f, 0.f, 0.f, 0.f);
    int tail = n & 3;
    if (blockIdx.x == 0 && threadIdx.x < tail) out[n4 * 4 + threadIdx.x] = 0.f;
}

// ---------- prep: per-chunk species counts + gCursor zeroing ----------

__global__ void prep_kernel(const int* __restrict__ cs, int n, int* __restrict__ chunkCounts,
                            int* __restrict__ zeroPtr, int zeroN) {
    __shared__ int cnt[NSPEC];
    if (threadIdx.x < NSPEC) cnt[threadIdx.x] = 0;
    __syncthreads();
    int i = blockIdx.x * blockDim.x + threadIdx.x;
    if (i < n) atomicAdd(&cnt[cs[i]], 1);
    if (zeroPtr) {
        for (int j = i; j < zeroN; j += gridDim.x * blockDim.x) zeroPtr[j] = 0;
    }
    __syncthreads();
    if (threadIdx.x < NSPEC) chunkCounts[blockIdx.x * NSPEC + threadIdx.x] = cnt[threadIdx.x];
}

// ---------- fused partition + dest kernel ----------
// blocks [0, nPart):        partition pairs into coarse center buckets (256 centers)
// blocks [nPart, +nChunks): compute dest[] for one 256-center chunk
// payload u: bits[31:10] = r (low 10 mantissa bits replaced), bits[9:2] = center&255,
// bits[1:0] = species.

__global__ void __launch_bounds__(PBDIM) partdest_kernel(
        const float* __restrict__ dirs, const int* __restrict__ pci,
        const int* __restrict__ nsi, const int* __restrict__ cs,
        const int* __restrict__ chunkCounts, int* __restrict__ dest,
        int* __restrict__ gCursor, unsigned* __restrict__ gBucket,
        int P, int NC, int nbkc, int nChunks, int nPart) {
    __shared__ int ldsraw[PLDSN];

    int tid = threadIdx.x;
    int lane = tid & 63, wv = tid >> 6;

    if ((int)blockIdx.x < nPart) {
        // ---------------- partition job ----------------
        unsigned* sSort = (unsigned*)ldsraw;          // CHUNK
        int* sHist = ldsraw + CHUNK;                  // MAXBC
        int* sOffs = sHist + MAXBC;                   // MAXBC
        int* sWaveTot = sOffs + MAXBC;                // 16

        int base = blockIdx.x * CHUNK;

        for (int i = tid; i < nbkc; i += PBDIM) sHist[i] = 0;
        __syncthreads();

        unsigned uu[IPT];
        int bb[IPT];
        #pragma unroll
        for (int j = 0; j < IPT; ++j) {
            int i = base + j * PBDIM + tid;
            int bkt = -1; unsigned u = 0;
            if (i < P) {
                float x = dirs[3 * i + 0], y = dirs[3 * i + 1], z = dirs[3 * i + 2];
                float r2 = x * x + y * y + z * z;
                if (r2 < RCUT * RCUT) {
                    float r = sqrtf(r2);
                    int c = pci[i];
                    bkt = c >> 8;
                    u = (__float_as_uint(r) & 0xFFFFFC00u) | ((unsigned)(c & 255) << 2) |
                        (unsigned)nsi[i];
                    atomicAdd(&sHist[bkt], 1);
                }
            }
            uu[j] = u; bb[j] = bkt;
        }
        __syncthreads();

        // block exclusive scan of sHist[0..nbkc) into sOffs (seg = 1 for nbkc <= 1024)
        int run = 0;
        if (tid < nbkc) { sOffs[tid] = 0; run = sHist[tid]; }
        int incl = run;
        #pragma unroll
        for (int off = 1; off < 64; off <<= 1) {
            int t = __shfl_up(incl, off);
            if (lane >= off) incl += t;
        }
        if (lane == 63) sWaveTot[wv] = incl;
        __syncthreads();
        int wbase = 0;
        for (int w = 0; w < wv; ++w) wbase += sWaveTot[w];
        if (tid < nbkc) sOffs[tid] = wbase + incl - run;
        __syncthreads();

        // scatter into LDS sorted order (sOffs becomes end-cursor per bucket)
        #pragma unroll
        for (int j = 0; j < IPT; ++j) {
            if (bb[j] >= 0) {
                int pos = atomicAdd(&sOffs[bb[j]], 1);
                sSort[pos] = uu[j];
            }
        }
        __syncthreads();

        // flush each bucket's contiguous run to its global region
        for (int b = tid; b < nbkc; b += PBDIM) {
            int c = sHist[b];
            if (!c) continue;
            int start = sOffs[b] - c;
            int g = atomicAdd(&gCursor[b], c);
            int lim = min(c, CAP - g);      // safety clamp
            unsigned* dst = gBucket + (size_t)b * CAP + g;
            for (int k = 0; k < lim; ++k) dst[k] = sSort[start + k];
        }
    } else {
        // ---------------- dest job: chunk cj (atomic-free wave reduce) ----------------
        int cj = blockIdx.x - nPart;
        if (cj >= nChunks) return;
        int* cOffs = ldsraw;          // 4
        int* wPart = ldsraw + 8;      // 16*2
        int* spAcc = ldsraw + 48;     // 8
        int* wCnt  = ldsraw + 64;     // 16*4

        int sp = wv & 3;
        int pref = 0, tot = 0;
        for (int c = (wv >> 2) * 64 + lane; c < nChunks; c += 256) {
            int v = chunkCounts[c * NSPEC + sp];
            tot += v;
            if (c < cj) pref += v;
        }
        #pragma unroll
        for (int off = 32; off; off >>= 1) {
            pref += __shfl_down(pref, off);
            tot  += __shfl_down(tot, off);
        }
        if (lane == 0) { wPart[wv * 2] = pref; wPart[wv * 2 + 1] = tot; }
        __syncthreads();

        if (tid < 4) {
            int p = 0, t = 0;
            for (int w = tid; w < 16; w += 4) { p += wPart[w * 2]; t += wPart[w * 2 + 1]; }
            spAcc[tid] = p; spAcc[4 + tid] = t;
        }
        __syncthreads();
        if (tid == 0) {
            int b = 0;
            #pragma unroll
            for (int s = 0; s < NSPEC; ++s) { cOffs[s] = b + spAcc[s]; b += spAcc[4 + s]; }
        }
        __syncthreads();

        int i = cj * 256 + tid;
        int s = (tid < 256 && i < NC) ? cs[i] : -1;
        int lanePrefix = 0;
        #pragma unroll
        for (int spp = 0; spp < NSPEC; ++spp) {
            unsigned long long b = __ballot(s == spp);
            if (lane == 0) wCnt[wv * 4 + spp] = __popcll(b);
            if (spp == s) lanePrefix = __popcll(b & ((1ull << lane) - 1ull));
        }
        __syncthreads();
        if (s >= 0) {
            int wp = 0;
            for (int w = 0; w < wv; ++w) wp += wCnt[w * 4 + s];
            dest[i] = cOffs[s] + wp + lanePrefix;
        }
    }
}

// ---------- accumulate: coarse bucket -> LDS sort -> ONE thread per (center,species) bin ----

__global__ void __launch_bounds__(PBDIM) accum_kernel(
        const int* __restrict__ gCursor, const unsigned* __restrict__ gBucket,
        const int* __restrict__ dest, float* __restrict__ out, int NC) {
    __shared__ unsigned sSort[CAP];
    __shared__ int sHist[1024];
    __shared__ int sOff[1024];
    __shared__ int sWaveTot[16];
    __shared__ int destLds[CPB];
    __shared__ float sStage[64 * ASTRIDE];

    int tid = threadIdx.x;
    int b = blockIdx.x;
    int cBase = b * CPB;
    int n = min(gCursor[b], CAP);
    const unsigned* src = gBucket + (size_t)b * CAP;

    sHist[tid] = 0;
    if (tid < CPB && cBase + tid < NC) destLds[tid] = dest[cBase + tid];
    __syncthreads();

    // pass 1: histogram over 1024 bins (bucket run is coalesced; re-read hits L2)
    for (int i = tid; i < n; i += PBDIM) atomicAdd(&sHist[src[i] & 1023u], 1);
    __syncthreads();

    // exclusive scan of 1024 bins
    int lane = tid & 63, wv = tid >> 6;
    int v = sHist[tid];
    int incl = v;
    #pragma unroll
    for (int off = 1; off < 64; off <<= 1) {
        int t = __shfl_up(incl, off);
        if (lane >= off) incl += t;
    }
    if (lane == 63) sWaveTot[wv] = incl;
    __syncthreads();
    int wbase = 0;
    for (int w = 0; w < wv; ++w) wbase += sWaveTot[w];
    sOff[tid] = wbase + incl - v;
    __syncthreads();

    // pass 2: scatter into LDS sorted order (sOff becomes end-cursor)
    for (int i = tid; i < n; i += PBDIM) {
        unsigned u = src[i];
        int pos = atomicAdd(&sOff[u & 1023u], 1);
        sSort[pos] = u;
    }
    __syncthreads();

    // my bin = tid = (centerLocal<<2)|species
    int end = sOff[tid], start = end - sHist[tid];
    float acc[36];
    #pragma unroll
    for (int j = 0; j < 36; ++j) acc[j] = 0.f;

    for (int p = start; p < end; ++p) {
        unsigned u = sSort[p];
        float r = __uint_as_float(u & 0xFFFFFC00u);
        float r2 = r * r;
        float fc = 0.5f * (__cosf(0.6283185307179586f * r) + 1.0f);  // cos(pi*r/RCUT)
        float q = __expf(-r2 * 0.04f);                                // exp(-r^2/25)
        float q2 = q * q;
        float bq[12];  // bq[n] = q^(n+1), two independent x q^2 chains
        bq[0] = q; bq[1] = q2;
        #pragma unroll
        for (int nn = 2; nn < 12; ++nn) bq[nn] = bq[nn - 2] * q2;
        float a0 = fc, a1 = fc * r, a2 = a1 * r, a3 = a2 * r;
        #pragma unroll
        for (int nn = 0; nn < 12; ++nn) acc[nn]      = fmaf(a0, bq[nn], acc[nn]);
        #pragma unroll
        for (int nn = 0; nn < 10; ++nn) acc[12 + nn] = fmaf(a1, bq[nn], acc[12 + nn]);
        #pragma unroll
        for (int nn = 0; nn < 8; ++nn)  acc[22 + nn] = fmaf(a2, bq[nn], acc[22 + nn]);
        #pragma unroll
        for (int nn = 0; nn < 6; ++nn)  acc[30 + nn] = fmaf(a3, bq[nn], acc[30 + nn]);
    }

    // stage + write out in four 64-row groups (stage buffer holds 64 rows)
    int nRows = min(CPB, NC - cBase);
    #pragma unroll 1
    for (int g = 0; g < 4; ++g) {
        if ((tid >> 8) == g) {
            // stage my bin: row = (tid>>2)&63, col = off_l + 4n + (tid&3)
            float* rowp = sStage + ((tid >> 2) & 63) * ASTRIDE + (tid & 3);
            #pragma unroll
            for (int nn = 0; nn < 12; ++nn) rowp[nn * 4]       = acc[nn];
            #pragma unroll
            for (int nn = 0; nn < 10; ++nn) rowp[48 + nn * 4]  = acc[12 + nn];
            #pragma unroll
            for (int nn = 0; nn < 8; ++nn)  rowp[88 + nn * 4]  = acc[22 + nn];
            #pragma unroll
            for (int nn = 0; nn < 6; ++nn)  rowp[120 + nn * 4] = acc[30 + nn];
        }
        __syncthreads();
        int gRows = min(64, nRows - g * 64);
        if (gRows > 0) {
            int lim = gRows * 36;
            for (int i = tid; i < lim; i += PBDIM) {
                int row = i / 36;
                int c4 = i - row * 36;
                float4 val = *(const float4*)(sStage + row * ASTRIDE + c4 * 4);
                *(float4*)(out + (size_t)destLds[g * 64 + row] * NFEAT + c4 * 4) = val;
            }
        }
        __syncthreads();
    }
}

// ---------- fallback: direct atomic scatter ----------

__global__ void pair_kernel(const float* __restrict__ dirs,
                            const int* __restrict__ pci,
                            const int* __restrict__ nsi,
                            const int* __restrict__ dest,
                            float* __restrict__ out, int P) {
    int i = blockIdx.x * blockDim.x + threadIdx.x;
    if (i >= P) return;
    float x = dirs[3 * i + 0], y = dirs[3 * i + 1], z = dirs[3 * i + 2];
    float r2 = x * x + y * y + z * z;
    float r = sqrtf(r2);
    if (r >= RCUT) return;
    float fc = 0.5f * (cosf(3.14159265358979323846f * r * (1.0f / RCUT)) + 1.0f);
    float q = expf(-r2 * (1.0f / (RCUT * RCUT)));
    int rowb = dest[pci[i]] * NFEAT;
    int s = nsi[i];
    float* o = out + rowb + s;
    float rl = fc;
    const int nmax[4] = {12, 10, 8, 6};
    const int offl[4] = {0, 48, 88, 120};
    #pragma unroll
    for (int l = 0; l < 4; ++l) {
        float e = q;
        for (int n = 0; n < nmax[l]; ++n) { atomicAdd(o + offl[l] + n * NSPEC, rl * e); e *= q; }
        rl *= r;
    }
}

extern "C" void kernel_launch(void* const* d_in, const int* in_sizes, int n_in,
                              void* d_out, int out_size, void* d_ws, size_t ws_size,
                              hipStream_t stream) {
    const float* dirs = (const float*)d_in[0];
    const int* pci = (const int*)d_in[1];
    const int* nsi = (const int*)d_in[2];
    const int* cs = (const int*)d_in[3];
    int P = in_sizes[1];
    int NC = in_sizes[3];
    float* out = (float*)d_out;

    int nChunks = (NC + 255) / 256;
    int nbkc = (NC + CPB - 1) / CPB;
    int nPart = (P + CHUNK - 1) / CHUNK;

    // ws layout (ints)
    int* chunkCounts  = (int*)d_ws;                      // nChunks*4
    int* dest         = chunkCounts + nChunks * NSPEC;   // NC
    int* gCursor      = dest + NC;                       // nbkc
    unsigned* gBucket = (unsigned*)(gCursor + nbkc);     // nbkc*CAP

    size_t need = ((size_t)(nChunks * NSPEC) + (size_t)NC + (size_t)nbkc +
                   (size_t)nbkc * CAP) * sizeof(int);
    bool fastPath = (ws_size >= need) && (nbkc <= MAXBC);

    if (fastPath) {
        prep_kernel<<<nChunks, 256, 0, stream>>>(cs, NC, chunkCounts, gCursor, nbkc);
        partdest_kernel<<<nPart + nChunks, PBDIM, 0, stream>>>(
            dirs, pci, nsi, cs, chunkCounts, dest, gCursor, gBucket,
            P, NC, nbkc, nChunks, nPart);
        accum_kernel<<<nbkc, PBDIM, 0, stream>>>(gCursor, gBucket, dest, out, NC);
    } else {
        // fallback: prep + dest-only partdest + atomic pair scatter
        prep_kernel<<<nChunks, 256, 0, stream>>>(cs, NC, chunkCounts, (int*)nullptr, 0);
        partdest_kernel<<<nChunks, PBDIM, 0, stream>>>(
            dirs, pci, nsi, cs, chunkCounts, dest, (int*)d_ws /*unused*/, (unsigned*)d_ws,
            0 /*P=0 -> no partition blocks*/, NC, nbkc, nChunks, 0);
        zero_f32<<<2048, 256, 0, stream>>>(out, out_size);
        pair_kernel<<<(P + 255) / 256, 256, 0, stream>>>(dirs, pci, nsi, dest, out, P);
    }
}